// Round 9
// baseline (324.208 us; speedup 1.0000x reference)
//
#include <hip/hip_runtime.h>
#include <math.h>

#define Y_ 1024
#define X_ 2048
#define YX_ (Y_*X_)
#define RAD_ 12
#define NT_ 25
#define ND_ 27
#define APC_ 15
#define PAD_ 16

struct W25 { float w[NT_]; };
struct D27 { float d[ND_]; };

// ---------------------------------------------------------------------------
// K1: Y-smooth (circular) of 7 channels, 16 rows/thread, 10-deep load
// batches, XCD-swizzled (unchanged from round 7).
// ---------------------------------------------------------------------------
__global__ __launch_bounds__(256) void ksmooth_y7c(
    const float* __restrict__ yin, const float* __restrict__ vin,
    float* __restrict__ out, W25 W)
{
  const int id = blockIdx.x;                  // nwg = 2*64*7 = 896
  const int w  = (id & 7) * 112 + (id >> 3);  // bijective XCD swizzle
  const int yg = w % 64, xh = (w / 64) & 1, z = w / 128;
  const int y0 = yg * 16;
  const int xo = xh * 1024 + threadIdx.x * 4;

  float4 acc[16];
#pragma unroll
  for (int j = 0; j < 16; ++j) acc[j] = make_float4(0.f, 0.f, 0.f, 0.f);

  if (z < 5) {
    const float* base = yin + z * YX_;
#pragma unroll
    for (int g = 0; g < 4; ++g) {
      float4 b[10];
#pragma unroll
      for (int i = 0; i < 10; ++i) {
        const int r = (y0 - RAD_ + 10*g + i + Y_) & (Y_ - 1);
        b[i] = *(const float4*)(base + r * X_ + xo);
      }
#pragma unroll
      for (int i = 0; i < 10; ++i) {
        const int t = 10*g + i;
#pragma unroll
        for (int j = 0; j < 16; ++j) {
          const int k = t - j;
          if (k >= 0 && k < NT_) {
            const float wk = W.w[k];
            acc[j].x += wk * b[i].x; acc[j].y += wk * b[i].y;
            acc[j].z += wk * b[i].z; acc[j].w += wk * b[i].w;
          }
        }
      }
    }
  } else {
    const int   c   = z - 5;
    const float sgn = (c == 0) ? -1.f : 1.f;
    const float* base = vin + c * YX_;
#pragma unroll
    for (int g = 0; g < 8; ++g) {
      float4 a5[5], b5[5];
#pragma unroll
      for (int i = 0; i < 5; ++i) {
        const int r = (y0 - RAD_ + 5*g + i + Y_) & (Y_ - 1);
        a5[i] = *(const float4*)(base + r * X_ + xo);
        b5[i] = *(const float4*)(base + (Y_ - 1 - r) * X_ + xo);
      }
#pragma unroll
      for (int i = 0; i < 5; ++i) {
        const int t = 5*g + i;
        float4 val;
        val.x = 0.5f * (a5[i].x + sgn * b5[i].x);
        val.y = 0.5f * (a5[i].y + sgn * b5[i].y);
        val.z = 0.5f * (a5[i].z + sgn * b5[i].z);
        val.w = 0.5f * (a5[i].w + sgn * b5[i].w);
#pragma unroll
        for (int j = 0; j < 16; ++j) {
          const int k = t - j;
          if (k >= 0 && k < NT_) {
            const float wk = W.w[k];
            acc[j].x += wk * val.x; acc[j].y += wk * val.y;
            acc[j].z += wk * val.z; acc[j].w += wk * val.w;
          }
        }
      }
    }
  }
#pragma unroll
  for (int j = 0; j < 16; ++j)
    *(float4*)(out + z * YX_ + (y0 + j) * X_ + xo) = acc[j];
}

// ---------------------------------------------------------------------------
// K2: kfused_lds — derivatives + algebra with LDS-SoA row staging.
// SoA layout: element x of a staged row lives at slot[x&3][x>>2]; a wave
// reading window element i hits lds[i&3][tid+(i>>2)] -> stride-1 across
// lanes -> 2 lanes/bank -> conflict-free. Double-buffered, 1 barrier/channel.
// ---------------------------------------------------------------------------
__device__ __forceinline__ void stage_row(
    float (&slot)[4][264], const float* __restrict__ src, int tid)
{
  float4 v = *(const float4*)(src + 4 * tid);
  slot[0][tid] = v.x; slot[1][tid] = v.y; slot[2][tid] = v.z; slot[3][tid] = v.w;
  if (tid < 8) {
    float4 v2 = *(const float4*)(src + 1024 + 4 * tid);
    slot[0][256+tid] = v2.x; slot[1][256+tid] = v2.y;
    slot[2][256+tid] = v2.z; slot[3][256+tid] = v2.w;
  }
}

// dX = 27-tap D-conv on center row; dY = 25-tap W-conv of 0.5*(up-down).
// Window wb[i] = row[x0-16+i] ~ L[row][i&3][tid+(i>>2)]. Validated tap math
// (rounds 4/6): dX[j] = sum_k D[k]*wb[3+j+k]; dY[j] = sum_k W[k]*db[j+k],
// db[i2] = 0.5*(u-d) at wb index 4+i2.
__device__ __forceinline__ void conv_lds(
    const float (&L)[3][4][264], int tid, const W25& W, const D27& D,
    float dX[4], float dY[4])
{
#pragma unroll
  for (int j = 0; j < 4; ++j) { dX[j] = 0.f; dY[j] = 0.f; }
#pragma unroll
  for (int i = 3; i <= 33; ++i) {
    const float v = L[1][i & 3][tid + (i >> 2)];
#pragma unroll
    for (int j = 0; j < 4; ++j) {
      const int k = i - 3 - j;
      if (k >= 0 && k < ND_) dX[j] += D.d[k] * v;
    }
  }
#pragma unroll
  for (int i = 4; i <= 31; ++i) {
    const float u = L[2][i & 3][tid + (i >> 2)];
    const float d = L[0][i & 3][tid + (i >> 2)];
    const float dv = 0.5f * (u - d);
#pragma unroll
    for (int j = 0; j < 4; ++j) {
      const int k = i - 4 - j;
      if (k >= 0 && k < NT_) dY[j] += W.w[k] * dv;
    }
  }
}

__global__ __launch_bounds__(256) void kfused_lds(
    const float* __restrict__ gY,    // 7ch y-smoothed (16-float pad before)
    const float* __restrict__ yin,   // raw y, 5ch
    const float* __restrict__ vin,   // raw v, 2ch
    float* __restrict__ B,           // 5ch out
    W25 W, D27 D)
{
  __shared__ float lds[2][3][4][264];          // 25.3 KB, double-buffered
  const int tid = threadIdx.x;
  const int id  = blockIdx.x;                  // nwg = 2048
  const int w   = (id & 7) * 256 + (id >> 3);  // XCD swizzle
  const int yy  = w & (Y_ - 1);
  const int xh  = w >> 10;
  const int xb  = xh * 1024;
  const int x0  = xb + 4 * tid;
  const int yu  = (yy + 1) & (Y_ - 1);
  const int yd  = (yy - 1) & (Y_ - 1);

  // symmetrized raw v at this row
  float v0[4], v1[4];
  {
    float4 a = *(const float4*)(vin + 0 * YX_ + yy * X_ + x0);
    float4 b = *(const float4*)(vin + 0 * YX_ + (Y_ - 1 - yy) * X_ + x0);
    float4 c = *(const float4*)(vin + 1 * YX_ + yy * X_ + x0);
    float4 d = *(const float4*)(vin + 1 * YX_ + (Y_ - 1 - yy) * X_ + x0);
    v0[0] = 0.5f*(a.x-b.x); v0[1] = 0.5f*(a.y-b.y);
    v0[2] = 0.5f*(a.z-b.z); v0[3] = 0.5f*(a.w-b.w);
    v1[0] = 0.5f*(c.x+d.x); v1[1] = 0.5f*(c.y+d.y);
    v1[2] = 0.5f*(c.z+d.z); v1[3] = 0.5f*(c.w+d.w);
  }

  float dXa[4], dYa[4], w_[4], trE[4];
  float ac0[4], ac1[4], ac2[4], ac3[4], ac4[4];

  // prologue: stage ch5 into buffer 0
  {
    const float* b5 = gY + 5 * YX_;
    stage_row(lds[0][0], b5 + yd * X_ + xb - 16, tid);
    stage_row(lds[0][1], b5 + yy * X_ + xb - 16, tid);
    stage_row(lds[0][2], b5 + yu * X_ + xb - 16, tid);
  }
  __syncthreads();

  // channel order: 5, 6, 0, 1, 2, 3, 4
#pragma unroll
  for (int ci = 0; ci < 7; ++ci) {
    if (ci < 6) {
      const int nch = (ci == 0) ? 6 : ci - 1;    // next channel (compile-time)
      const float* bn = gY + nch * YX_;
      const int nb = (ci + 1) & 1;
      stage_row(lds[nb][0], bn + yd * X_ + xb - 16, tid);
      stage_row(lds[nb][1], bn + yy * X_ + xb - 16, tid);
      stage_row(lds[nb][2], bn + yu * X_ + xb - 16, tid);
    }
    float dX[4], dY[4];
    conv_lds(lds[ci & 1], tid, W, D, dX, dY);
    if (ci == 0) {
#pragma unroll
      for (int j = 0; j < 4; ++j) { dXa[j] = dX[j]; dYa[j] = dY[j]; }
    } else if (ci == 1) {
#pragma unroll
      for (int j = 0; j < 4; ++j) {
        w_[j]  = -0.5f * (dXa[j] - dY[j]);       // vorticity O[0][1]
        trE[j] = dYa[j] + dX[j];
      }
    } else {
#pragma unroll
      for (int j = 0; j < 4; ++j) {
        const float t = v0[j] * dY[j] + v1[j] * dX[j];
        if (ci == 2) ac0[j] = t;                 // static after unroll
        if (ci == 3) ac1[j] = t;
        if (ci == 4) ac2[j] = t;
        if (ci == 5) ac3[j] = t;
        if (ci == 6) ac4[j] = t;
      }
    }
    __syncthreads();
  }

  // raw fields + algebra epilogue
  float rm[5][4];
#pragma unroll
  for (int zc = 0; zc < 5; ++zc) {
    float4 t = *(const float4*)(yin + zc * YX_ + yy * X_ + x0);
    rm[zc][0] = t.x; rm[zc][1] = t.y; rm[zc][2] = t.z; rm[zc][3] = t.w;
  }

  float o[5][4];
#pragma unroll
  for (int j = 0; j < 4; ++j) {
    const float m00r = rm[0][j], m01r = rm[1][j], m10r = rm[2][j], m11r = rm[3][j];
    const float sr   = rm[4][j];
    const float wj   = w_[j];
    const float trm  = m00r + m11r;

    const float lhs00 = ac0[j] + wj * (m10r + m01r);
    const float lhs01 = ac1[j] + wj * (m11r - m00r);
    const float lhs10 = ac2[j] + wj * (m11r - m00r);
    const float lhs11 = ac3[j] - wj * (m01r + m10r);

    const float f  = -(0.11f - 0.099f * sr)
                   + (0.767f + 0.055f * sr) * trE[j]
                   + (0.732f - 0.59f  * sr) * trm;
    const float cd = (0.069f - 0.048f * sr) * trm;
    const float sd = -ac4[j];

    const int   xg   = x0 + j;
    const float mask = (xg < APC_ || xg >= X_ - APC_) ? 0.f : 1.f;
    o[0][j] = mask * (f * m00r + cd - lhs00);
    o[1][j] = mask * (f * m01r      - lhs01);
    o[2][j] = mask * (f * m10r      - lhs10);
    o[3][j] = mask * (f * m11r      - lhs11);
    o[4][j] = mask * sd;
  }
#pragma unroll
  for (int zc = 0; zc < 5; ++zc)
    *(float4*)(B + zc * YX_ + yy * X_ + x0) =
        make_float4(o[zc][0], o[zc][1], o[zc][2], o[zc][3]);
}

// ---------------------------------------------------------------------------
// K3: X-smooth (edge-replicate) of 5ch, buf[28] pattern (unchanged).
// ---------------------------------------------------------------------------
__global__ __launch_bounds__(256) void kxsmooth(
    const float* __restrict__ in, float* __restrict__ out, W25 W)
{
  const int z  = blockIdx.z;
  const int yy = blockIdx.y;
  const int x0 = (blockIdx.x * 256 + threadIdx.x) * 4;
  const float* row = in + z * YX_ + yy * X_;

  float buf[28];
  if (x0 >= RAD_ && x0 + 4 + RAD_ <= X_) {
#pragma unroll
    for (int i = 0; i < 7; ++i) {
      float4 t = *(const float4*)(row + x0 - RAD_ + 4 * i);
      buf[4*i+0] = t.x; buf[4*i+1] = t.y; buf[4*i+2] = t.z; buf[4*i+3] = t.w;
    }
  } else {
#pragma unroll
    for (int i = 0; i < 28; ++i) {
      int xx = x0 - RAD_ + i;
      xx = xx < 0 ? 0 : (xx > X_ - 1 ? X_ - 1 : xx);
      buf[i] = row[xx];
    }
  }
  float a0 = 0.f, a1 = 0.f, a2 = 0.f, a3 = 0.f;
#pragma unroll
  for (int t = 0; t < NT_; ++t) {
    const float wk = W.w[t];
    a0 += wk * buf[t + 0];
    a1 += wk * buf[t + 1];
    a2 += wk * buf[t + 2];
    a3 += wk * buf[t + 3];
  }
  *(float4*)(out + z * YX_ + yy * X_ + x0) = make_float4(a0, a1, a2, a3);
}

// ---------------------------------------------------------------------------
// K4: Y-smooth (circular) of 5ch, 16 rows/thread, batched, XCD-swizzled
// (unchanged).
// ---------------------------------------------------------------------------
__global__ __launch_bounds__(256) void ksmooth_y5c(
    const float* __restrict__ in, float* __restrict__ out, W25 W)
{
  const int id = blockIdx.x;                  // nwg = 2*64*5 = 640
  const int w  = (id & 7) * 80 + (id >> 3);
  const int yg = w % 64, xh = (w / 64) & 1, z = w / 128;
  const int y0 = yg * 16;
  const int xo = xh * 1024 + threadIdx.x * 4;
  const float* base = in + z * YX_;

  float4 acc[16];
#pragma unroll
  for (int j = 0; j < 16; ++j) acc[j] = make_float4(0.f, 0.f, 0.f, 0.f);

#pragma unroll
  for (int g = 0; g < 4; ++g) {
    float4 b[10];
#pragma unroll
    for (int i = 0; i < 10; ++i) {
      const int r = (y0 - RAD_ + 10*g + i + Y_) & (Y_ - 1);
      b[i] = *(const float4*)(base + r * X_ + xo);
    }
#pragma unroll
    for (int i = 0; i < 10; ++i) {
      const int t = 10*g + i;
#pragma unroll
      for (int j = 0; j < 16; ++j) {
        const int k = t - j;
        if (k >= 0 && k < NT_) {
          const float wk = W.w[k];
          acc[j].x += wk * b[i].x; acc[j].y += wk * b[i].y;
          acc[j].z += wk * b[i].z; acc[j].w += wk * b[i].w;
        }
      }
    }
  }
#pragma unroll
  for (int j = 0; j < 16; ++j)
    *(float4*)(out + z * YX_ + (y0 + j) * X_ + xo) = acc[j];
}

// ---------------------------------------------------------------------------
extern "C" void kernel_launch(void* const* d_in, const int* in_sizes, int n_in,
                              void* d_out, int out_size, void* d_ws, size_t ws_size,
                              hipStream_t stream)
{
  const float* yin = (const float*)d_in[0];   // (5, 1024, 2048) f32
  const float* vin = (const float*)d_in[1];   // (2, 1024, 2048) f32
  float* out = (float*)d_out;                 // (5, 1024, 2048) f32

  // ws: [PAD_][gY: 7ch][B: 5ch].  C aliases gY (dead after kfused_lds).
  float* gY = (float*)d_ws + PAD_;
  float* B  = gY + 7 * (size_t)YX_;
  float* C  = gY;

  W25 W; D27 D;
  double wd[NT_], s = 0.0;
  for (int i = 0; i < NT_; ++i) {
    const double x = i - RAD_;
    wd[i] = exp(-0.5 * (x / 3.0) * (x / 3.0));
    s += wd[i];
  }
  for (int i = 0; i < NT_; ++i) W.w[i] = (float)(wd[i] / s);
  for (int t = 0; t < ND_; ++t) {
    const double a = (t - 2 >= 0 && t - 2 < NT_) ? wd[t - 2] / s : 0.0;
    const double b = (t < NT_) ? wd[t] / s : 0.0;
    D.d[t] = (float)(0.5 * (a - b));
  }

  ksmooth_y7c<<<896,  256, 0, stream>>>(yin, vin, gY, W);
  kfused_lds <<<2048, 256, 0, stream>>>(gY, yin, vin, B, W, D);
  kxsmooth   <<<dim3(2, 1024, 5), 256, 0, stream>>>(B, C, W);
  ksmooth_y5c<<<640,  256, 0, stream>>>(C, out, W);
}

// Round 10
// 211.702 us; speedup vs baseline: 1.5314x; 1.5314x over previous
//
#include <hip/hip_runtime.h>
#include <math.h>

#define Y_ 1024
#define X_ 2048
#define YX_ (Y_*X_)
#define RAD_ 12
#define NT_ 25
#define ND_ 27
#define APC_ 15
#define PAD_ 16

struct W25 { float w[NT_]; };
struct D27 { float d[ND_]; };

// ---------------------------------------------------------------------------
// K1: Y-smooth (circular) of 7 channels, 16 rows/thread, 10-deep load
// batches, XCD-swizzled (unchanged from rounds 7/8).
// ---------------------------------------------------------------------------
__global__ __launch_bounds__(256) void ksmooth_y7c(
    const float* __restrict__ yin, const float* __restrict__ vin,
    float* __restrict__ out, W25 W)
{
  const int id = blockIdx.x;                  // nwg = 2*64*7 = 896
  const int w  = (id & 7) * 112 + (id >> 3);  // bijective XCD swizzle
  const int yg = w % 64, xh = (w / 64) & 1, z = w / 128;
  const int y0 = yg * 16;
  const int xo = xh * 1024 + threadIdx.x * 4;

  float4 acc[16];
#pragma unroll
  for (int j = 0; j < 16; ++j) acc[j] = make_float4(0.f, 0.f, 0.f, 0.f);

  if (z < 5) {
    const float* base = yin + z * YX_;
#pragma unroll
    for (int g = 0; g < 4; ++g) {
      float4 b[10];
#pragma unroll
      for (int i = 0; i < 10; ++i) {
        const int r = (y0 - RAD_ + 10*g + i + Y_) & (Y_ - 1);
        b[i] = *(const float4*)(base + r * X_ + xo);
      }
#pragma unroll
      for (int i = 0; i < 10; ++i) {
        const int t = 10*g + i;
#pragma unroll
        for (int j = 0; j < 16; ++j) {
          const int k = t - j;
          if (k >= 0 && k < NT_) {
            const float wk = W.w[k];
            acc[j].x += wk * b[i].x; acc[j].y += wk * b[i].y;
            acc[j].z += wk * b[i].z; acc[j].w += wk * b[i].w;
          }
        }
      }
    }
  } else {
    const int   c   = z - 5;
    const float sgn = (c == 0) ? -1.f : 1.f;
    const float* base = vin + c * YX_;
#pragma unroll
    for (int g = 0; g < 8; ++g) {
      float4 a5[5], b5[5];
#pragma unroll
      for (int i = 0; i < 5; ++i) {
        const int r = (y0 - RAD_ + 5*g + i + Y_) & (Y_ - 1);
        a5[i] = *(const float4*)(base + r * X_ + xo);
        b5[i] = *(const float4*)(base + (Y_ - 1 - r) * X_ + xo);
      }
#pragma unroll
      for (int i = 0; i < 5; ++i) {
        const int t = 5*g + i;
        float4 val;
        val.x = 0.5f * (a5[i].x + sgn * b5[i].x);
        val.y = 0.5f * (a5[i].y + sgn * b5[i].y);
        val.z = 0.5f * (a5[i].z + sgn * b5[i].z);
        val.w = 0.5f * (a5[i].w + sgn * b5[i].w);
#pragma unroll
        for (int j = 0; j < 16; ++j) {
          const int k = t - j;
          if (k >= 0 && k < NT_) {
            const float wk = W.w[k];
            acc[j].x += wk * val.x; acc[j].y += wk * val.y;
            acc[j].z += wk * val.z; acc[j].w += wk * val.w;
          }
        }
      }
    }
  }
#pragma unroll
  for (int j = 0; j < 16; ++j)
    *(float4*)(out + z * YX_ + (y0 + j) * X_ + xo) = acc[j];
}

// ---------------------------------------------------------------------------
// K2: kfused_lds2 — derivatives + algebra with LDS-SoA row staging.
// Round-9 LDS layout (measured 0 bank conflicts) but with the spill fixed:
//   * channel loop NOT unrolled (#pragma unroll 1) -> small scheduling
//     region, one shared conv body
//   * static register targets via switch(ci)
//   * __launch_bounds__(256,4) caps VGPR at 128
// SoA: element x of a staged row lives at slot[x&3][x>>2]; wave reads are
// stride-1 across lanes (2 lanes/bank = free).
// ---------------------------------------------------------------------------
__device__ __forceinline__ void stage_row(
    float (&slot)[4][264], const float* __restrict__ src, int tid)
{
  float4 v = *(const float4*)(src + 4 * tid);
  slot[0][tid] = v.x; slot[1][tid] = v.y; slot[2][tid] = v.z; slot[3][tid] = v.w;
  if (tid < 8) {
    float4 v2 = *(const float4*)(src + 1024 + 4 * tid);
    slot[0][256+tid] = v2.x; slot[1][256+tid] = v2.y;
    slot[2][256+tid] = v2.z; slot[3][256+tid] = v2.w;
  }
}

// dX = 27-tap D-conv on center row; dY = 25-tap W-conv of 0.5*(up-down).
// wb[i] ~ L[row][i&3][tid+(i>>2)], wb[i] = row[x0-16+i]. Tap math validated
// rounds 4-9: dX[j] = sum_k D[k]*wb[3+j+k]; dY[j] = sum_k W[k]*db[j+k] with
// db at wb index 4+idx.
__device__ __forceinline__ void conv_lds(
    const float (&L)[3][4][264], int tid, const W25& W, const D27& D,
    float dX[4], float dY[4])
{
#pragma unroll
  for (int j = 0; j < 4; ++j) { dX[j] = 0.f; dY[j] = 0.f; }
#pragma unroll
  for (int i = 3; i <= 33; ++i) {
    const float v = L[1][i & 3][tid + (i >> 2)];
#pragma unroll
    for (int j = 0; j < 4; ++j) {
      const int k = i - 3 - j;
      if (k >= 0 && k < ND_) dX[j] += D.d[k] * v;
    }
  }
#pragma unroll
  for (int i = 4; i <= 31; ++i) {
    const float u = L[2][i & 3][tid + (i >> 2)];
    const float d = L[0][i & 3][tid + (i >> 2)];
    const float dv = 0.5f * (u - d);
#pragma unroll
    for (int j = 0; j < 4; ++j) {
      const int k = i - 4 - j;
      if (k >= 0 && k < NT_) dY[j] += W.w[k] * dv;
    }
  }
}

__global__ __launch_bounds__(256, 4) void kfused_lds2(
    const float* __restrict__ gY,    // 7ch y-smoothed (16-float pad before)
    const float* __restrict__ yin,   // raw y, 5ch
    const float* __restrict__ vin,   // raw v, 2ch
    float* __restrict__ B,           // 5ch out
    W25 W, D27 D)
{
  __shared__ float lds[2][3][4][264];          // 25.3 KB, double-buffered
  const int tid = threadIdx.x;
  const int id  = blockIdx.x;                  // nwg = 2048
  const int w   = (id & 7) * 256 + (id >> 3);  // XCD swizzle
  const int yy  = w & (Y_ - 1);
  const int xh  = w >> 10;
  const int xb  = xh * 1024;
  const int x0  = xb + 4 * tid;
  const int yu  = (yy + 1) & (Y_ - 1);
  const int yd  = (yy - 1) & (Y_ - 1);

  // symmetrized raw v at this row
  float v0[4], v1[4];
  {
    float4 a = *(const float4*)(vin + 0 * YX_ + yy * X_ + x0);
    float4 b = *(const float4*)(vin + 0 * YX_ + (Y_ - 1 - yy) * X_ + x0);
    float4 c = *(const float4*)(vin + 1 * YX_ + yy * X_ + x0);
    float4 d = *(const float4*)(vin + 1 * YX_ + (Y_ - 1 - yy) * X_ + x0);
    v0[0] = 0.5f*(a.x-b.x); v0[1] = 0.5f*(a.y-b.y);
    v0[2] = 0.5f*(a.z-b.z); v0[3] = 0.5f*(a.w-b.w);
    v1[0] = 0.5f*(c.x+d.x); v1[1] = 0.5f*(c.y+d.y);
    v1[2] = 0.5f*(c.z+d.z); v1[3] = 0.5f*(c.w+d.w);
  }

  float dXa[4], dYa[4], w_[4], trE[4];
  float ac0[4], ac1[4], ac2[4], ac3[4], ac4[4];

  // prologue: stage ch5 into buffer 0
  {
    const float* b5 = gY + 5 * YX_;
    stage_row(lds[0][0], b5 + yd * X_ + xb - 16, tid);
    stage_row(lds[0][1], b5 + yy * X_ + xb - 16, tid);
    stage_row(lds[0][2], b5 + yu * X_ + xb - 16, tid);
  }
  __syncthreads();

  // channel order: 5, 6, 0, 1, 2, 3, 4   (nch = ci==0 ? 6 : ci-1)
#pragma unroll 1
  for (int ci = 0; ci < 7; ++ci) {
    if (ci < 6) {
      const int nch = (ci == 0) ? 6 : ci - 1;
      const float* bn = gY + nch * YX_;
      float (&nb)[3][4][264] = lds[(ci + 1) & 1];
      stage_row(nb[0], bn + yd * X_ + xb - 16, tid);
      stage_row(nb[1], bn + yy * X_ + xb - 16, tid);
      stage_row(nb[2], bn + yu * X_ + xb - 16, tid);
    }
    float dX[4], dY[4];
    conv_lds(lds[ci & 1], tid, W, D, dX, dY);
    switch (ci) {
      case 0:
#pragma unroll
        for (int j = 0; j < 4; ++j) { dXa[j] = dX[j]; dYa[j] = dY[j]; }
        break;
      case 1:
#pragma unroll
        for (int j = 0; j < 4; ++j) {
          w_[j]  = -0.5f * (dXa[j] - dY[j]);   // vorticity O[0][1]
          trE[j] = dYa[j] + dX[j];
        }
        break;
      case 2:
#pragma unroll
        for (int j = 0; j < 4; ++j) ac0[j] = v0[j]*dY[j] + v1[j]*dX[j];
        break;
      case 3:
#pragma unroll
        for (int j = 0; j < 4; ++j) ac1[j] = v0[j]*dY[j] + v1[j]*dX[j];
        break;
      case 4:
#pragma unroll
        for (int j = 0; j < 4; ++j) ac2[j] = v0[j]*dY[j] + v1[j]*dX[j];
        break;
      case 5:
#pragma unroll
        for (int j = 0; j < 4; ++j) ac3[j] = v0[j]*dY[j] + v1[j]*dX[j];
        break;
      default:
#pragma unroll
        for (int j = 0; j < 4; ++j) ac4[j] = v0[j]*dY[j] + v1[j]*dX[j];
        break;
    }
    __syncthreads();
  }

  // raw fields + algebra epilogue
  float rm[5][4];
#pragma unroll
  for (int zc = 0; zc < 5; ++zc) {
    float4 t = *(const float4*)(yin + zc * YX_ + yy * X_ + x0);
    rm[zc][0] = t.x; rm[zc][1] = t.y; rm[zc][2] = t.z; rm[zc][3] = t.w;
  }

  float o[5][4];
#pragma unroll
  for (int j = 0; j < 4; ++j) {
    const float m00r = rm[0][j], m01r = rm[1][j], m10r = rm[2][j], m11r = rm[3][j];
    const float sr   = rm[4][j];
    const float wj   = w_[j];
    const float trm  = m00r + m11r;

    const float lhs00 = ac0[j] + wj * (m10r + m01r);
    const float lhs01 = ac1[j] + wj * (m11r - m00r);
    const float lhs10 = ac2[j] + wj * (m11r - m00r);
    const float lhs11 = ac3[j] - wj * (m01r + m10r);

    const float f  = -(0.11f - 0.099f * sr)
                   + (0.767f + 0.055f * sr) * trE[j]
                   + (0.732f - 0.59f  * sr) * trm;
    const float cd = (0.069f - 0.048f * sr) * trm;
    const float sd = -ac4[j];

    const int   xg   = x0 + j;
    const float mask = (xg < APC_ || xg >= X_ - APC_) ? 0.f : 1.f;
    o[0][j] = mask * (f * m00r + cd - lhs00);
    o[1][j] = mask * (f * m01r      - lhs01);
    o[2][j] = mask * (f * m10r      - lhs10);
    o[3][j] = mask * (f * m11r      - lhs11);
    o[4][j] = mask * sd;
  }
#pragma unroll
  for (int zc = 0; zc < 5; ++zc)
    *(float4*)(B + zc * YX_ + yy * X_ + x0) =
        make_float4(o[zc][0], o[zc][1], o[zc][2], o[zc][3]);
}

// ---------------------------------------------------------------------------
// K3: X-smooth (edge-replicate) of 5ch, buf[28] pattern (unchanged).
// ---------------------------------------------------------------------------
__global__ __launch_bounds__(256) void kxsmooth(
    const float* __restrict__ in, float* __restrict__ out, W25 W)
{
  const int z  = blockIdx.z;
  const int yy = blockIdx.y;
  const int x0 = (blockIdx.x * 256 + threadIdx.x) * 4;
  const float* row = in + z * YX_ + yy * X_;

  float buf[28];
  if (x0 >= RAD_ && x0 + 4 + RAD_ <= X_) {
#pragma unroll
    for (int i = 0; i < 7; ++i) {
      float4 t = *(const float4*)(row + x0 - RAD_ + 4 * i);
      buf[4*i+0] = t.x; buf[4*i+1] = t.y; buf[4*i+2] = t.z; buf[4*i+3] = t.w;
    }
  } else {
#pragma unroll
    for (int i = 0; i < 28; ++i) {
      int xx = x0 - RAD_ + i;
      xx = xx < 0 ? 0 : (xx > X_ - 1 ? X_ - 1 : xx);
      buf[i] = row[xx];
    }
  }
  float a0 = 0.f, a1 = 0.f, a2 = 0.f, a3 = 0.f;
#pragma unroll
  for (int t = 0; t < NT_; ++t) {
    const float wk = W.w[t];
    a0 += wk * buf[t + 0];
    a1 += wk * buf[t + 1];
    a2 += wk * buf[t + 2];
    a3 += wk * buf[t + 3];
  }
  *(float4*)(out + z * YX_ + yy * X_ + x0) = make_float4(a0, a1, a2, a3);
}

// ---------------------------------------------------------------------------
// K4: Y-smooth (circular) of 5ch, 16 rows/thread, batched, XCD-swizzled
// (unchanged).
// ---------------------------------------------------------------------------
__global__ __launch_bounds__(256) void ksmooth_y5c(
    const float* __restrict__ in, float* __restrict__ out, W25 W)
{
  const int id = blockIdx.x;                  // nwg = 2*64*5 = 640
  const int w  = (id & 7) * 80 + (id >> 3);
  const int yg = w % 64, xh = (w / 64) & 1, z = w / 128;
  const int y0 = yg * 16;
  const int xo = xh * 1024 + threadIdx.x * 4;
  const float* base = in + z * YX_;

  float4 acc[16];
#pragma unroll
  for (int j = 0; j < 16; ++j) acc[j] = make_float4(0.f, 0.f, 0.f, 0.f);

#pragma unroll
  for (int g = 0; g < 4; ++g) {
    float4 b[10];
#pragma unroll
    for (int i = 0; i < 10; ++i) {
      const int r = (y0 - RAD_ + 10*g + i + Y_) & (Y_ - 1);
      b[i] = *(const float4*)(base + r * X_ + xo);
    }
#pragma unroll
    for (int i = 0; i < 10; ++i) {
      const int t = 10*g + i;
#pragma unroll
      for (int j = 0; j < 16; ++j) {
        const int k = t - j;
        if (k >= 0 && k < NT_) {
          const float wk = W.w[k];
          acc[j].x += wk * b[i].x; acc[j].y += wk * b[i].y;
          acc[j].z += wk * b[i].z; acc[j].w += wk * b[i].w;
        }
      }
    }
  }
#pragma unroll
  for (int j = 0; j < 16; ++j)
    *(float4*)(out + z * YX_ + (y0 + j) * X_ + xo) = acc[j];
}

// ---------------------------------------------------------------------------
extern "C" void kernel_launch(void* const* d_in, const int* in_sizes, int n_in,
                              void* d_out, int out_size, void* d_ws, size_t ws_size,
                              hipStream_t stream)
{
  const float* yin = (const float*)d_in[0];   // (5, 1024, 2048) f32
  const float* vin = (const float*)d_in[1];   // (2, 1024, 2048) f32
  float* out = (float*)d_out;                 // (5, 1024, 2048) f32

  // ws: [PAD_][gY: 7ch][B: 5ch].  C aliases gY (dead after kfused_lds2).
  float* gY = (float*)d_ws + PAD_;
  float* B  = gY + 7 * (size_t)YX_;
  float* C  = gY;

  W25 W; D27 D;
  double wd[NT_], s = 0.0;
  for (int i = 0; i < NT_; ++i) {
    const double x = i - RAD_;
    wd[i] = exp(-0.5 * (x / 3.0) * (x / 3.0));
    s += wd[i];
  }
  for (int i = 0; i < NT_; ++i) W.w[i] = (float)(wd[i] / s);
  for (int t = 0; t < ND_; ++t) {
    const double a = (t - 2 >= 0 && t - 2 < NT_) ? wd[t - 2] / s : 0.0;
    const double b = (t < NT_) ? wd[t] / s : 0.0;
    D.d[t] = (float)(0.5 * (a - b));
  }

  ksmooth_y7c<<<896,  256, 0, stream>>>(yin, vin, gY, W);
  kfused_lds2<<<2048, 256, 0, stream>>>(gY, yin, vin, B, W, D);
  kxsmooth   <<<dim3(2, 1024, 5), 256, 0, stream>>>(B, C, W);
  ksmooth_y5c<<<640,  256, 0, stream>>>(C, out, W);
}